// Round 5
// baseline (341.156 us; speedup 1.0000x reference)
//
#include <hip/hip_runtime.h>
#include <math.h>

#define NB 2
#define SEQL 4096
#define NH 16
#define HD 128
#define HDV 128
#define CHK 1024
#define NC 4
#define BQ 128
#define BK 64
#define KSTR 136       // legacy: 128 + 8 pad (u16 units)
#define VSTR 72        // legacy: 64 + 8 pad (u16 units)
#define OUTW 2048      // NH*HDV
#define NEGB (-1e30f)
#define L2B64 0.20762050593045702f  // log2(10000)/64

typedef _Float16 f16x8 __attribute__((ext_vector_type(8)));
typedef float f32x4 __attribute__((ext_vector_type(4)));
typedef unsigned short u16x8 __attribute__((ext_vector_type(8)));

static __device__ __forceinline__ unsigned short f2h(float f) {
  return __builtin_bit_cast(unsigned short, (_Float16)f);
}
static __device__ __forceinline__ f16x8 ld8(const unsigned short* p) {
  return __builtin_bit_cast(f16x8, *(const u16x8*)p);
}
// Range-reduced fast sincos: v_sin/v_cos need reduced args (ISA: reduce via fract).
static __device__ __forceinline__ void fast_sincos(float t, float* sn, float* cs) {
  const float INV2PI = 0.15915494309189535f;
  const float TWOPI  = 6.283185307179586f;
  float rev = t * INV2PI;
  rev -= floorf(rev);
  float ang = rev * TWOPI;
  *sn = __sinf(ang);
  *cs = __cosf(ang);
}
// async global->LDS, 16 B per lane; LDS dest is wave-uniform base + lane*16.
static __device__ __forceinline__ void gload16(const void* g, void* l) {
  __builtin_amdgcn_global_load_lds(
      (const __attribute__((address_space(1))) unsigned int*)g,
      (__attribute__((address_space(3))) unsigned int*)l, 16, 0, 0);
}

// 16-lane butterfly reductions on the VALU pipe via DPP (replaces ds_swizzle-based
// __shfl_xor: ~4cy/step vs ~35cy/step). Steps stay within each 16-lane row:
// quad_perm ^1 (0xB1), quad_perm ^2 (0x4E), row_half_mirror (0x141), row_mirror (0x140).
#define DPPF(x, ctrl)                                                            \
  __builtin_bit_cast(float, __builtin_amdgcn_update_dpp(                         \
      __builtin_bit_cast(int, x), __builtin_bit_cast(int, x), ctrl, 0xF, 0xF, true))
static __device__ __forceinline__ float dpp16_max(float x) {
  x = fmaxf(x, DPPF(x, 0xB1));
  x = fmaxf(x, DPPF(x, 0x4E));
  x = fmaxf(x, DPPF(x, 0x141));
  x = fmaxf(x, DPPF(x, 0x140));
  return x;
}
static __device__ __forceinline__ float dpp16_sum(float x) {
  x += DPPF(x, 0xB1);
  x += DPPF(x, 0x4E);
  x += DPPF(x, 0x141);
  x += DPPF(x, 0x140);
  return x;
}

// ======================= PREPASS =======================
// Part A (blocks [0,4096)): RoPE(K) -> f16, per-tile-contiguous, XOR-swizzled.
//   element (r,dd) of tile -> u16 offset (r*128+dd) ^ ((r&7)<<3)
// Part B (blocks [4096,6144)): V -> f16 transposed [vc][kk] per 64-row tile,
//   element (vc,kk) -> u16 offset (vc*64+kk) ^ ((vc&7)<<3)
__global__ __launch_bounds__(256) void megalodon_prep(
    const float* __restrict__ k, const float* __restrict__ v,
    unsigned short* __restrict__ kr, unsigned short* __restrict__ vt,
    const int* __restrict__ startp) {
  const int tid = threadIdx.x;
  const int blk = blockIdx.x;
  if (blk < 4096) {
    const int s0 = startp[0];
    const int gr = blk * 32 + (tid >> 3);   // (b*L+l)*H + h
    const int c0 = (tid & 7) * 8;           // dd block [0,64)
    const int h  = gr & 15;
    const int bl = gr >> 4;
    const int l  = bl & (SEQL - 1);
    const int b  = bl >> 12;
    const int n  = l >> 10;
    const int rc = l & (CHK - 1);
    const int jt = rc >> 6;
    const int r  = rc & 63;
    const float* kp = k + (size_t)gr * HD;
    float xa[8], xb[8];
    *(f32x4*)&xa[0] = *(const f32x4*)(kp + c0);
    *(f32x4*)&xa[4] = *(const f32x4*)(kp + c0 + 4);
    *(f32x4*)&xb[0] = *(const f32x4*)(kp + c0 + 64);
    *(f32x4*)&xb[4] = *(const f32x4*)(kp + c0 + 68);
    u16x8 lo, hi;
#pragma unroll
    for (int jj = 0; jj < 8; ++jj) {
      const int dd = c0 + jj;
      float freq = exp2f(-L2B64 * (float)dd);
      float t = (float)(l + s0) * freq;
      float sn, cs;
      fast_sincos(t, &sn, &cs);
      lo[jj] = f2h(xa[jj] * cs - xb[jj] * sn);
      hi[jj] = f2h(xb[jj] * cs + xa[jj] * sn);
    }
    unsigned short* dst = kr + ((size_t)(((b * NH + h) * NC + n) * 16 + jt)) * 8192;
    const int sw = (r & 7) << 3;
    *(u16x8*)&dst[(r * 128 + c0) ^ sw]      = lo;
    *(u16x8*)&dst[(r * 128 + c0 + 64) ^ sw] = hi;
  } else {
    const int tv = blk - 4096;
    const int jt = tv & 15;
    const int n  = (tv >> 4) & 3;
    const int h  = (tv >> 6) & 15;
    const int b  = tv >> 10;
    unsigned short* dst = vt + ((size_t)(((b * NH + h) * NC + n) * 16 + jt)) * 8192;
#pragma unroll
    for (int it = 0; it < 4; ++it) {
      const int idx = tid + it * 256;
      const int vc = idx & 127;
      const int kg = idx >> 7;
      const int lbase = n * CHK + jt * 64 + kg * 8;
      u16x8 vv;
#pragma unroll
      for (int i = 0; i < 8; ++i)
        vv[i] = f2h(v[((size_t)(b * SEQL + lbase + i) * NH + h) * HDV + vc]);
      *(u16x8*)&dst[(vc * 64 + kg * 8) ^ ((vc & 7) << 3)] = vv;
    }
  }
}

// ======================= MAIN v5: 8-wave blocks (512 thr), 16 Q-rows/wave, =======================
// == 64KB LDS (K dbuf + V dbuf, sP aliased in retired K half) -> 2 blocks/CU = 16 waves/CU. ======
// == __launch_bounds__(512,4): VGPR cap 128; per-wave live set ~105 (halved state) fits. =========
__global__ __launch_bounds__(512, 4) void megalodon_attn2(
    const float* __restrict__ q,
    const unsigned short* __restrict__ kr,
    const unsigned short* __restrict__ vt,
    float* __restrict__ out,
    const int* __restrict__ startp) {

  // LDS (bytes): sK0 @0, sK1 @16384, sV0 @32768, sV1 @49152 -> 64 KiB.
  // sP for iter j ALIASES sK[j&1]: 8 waves x 2KB = 16KB; written after B2 (QK reads done),
  // read before B3 (then iter j+1 restages that half with tile j+2).
  __shared__ __align__(16) unsigned short smem[32768];

  const int tid  = threadIdx.x;
  const int lane = tid & 63;
  const int wv   = tid >> 6;   // 0..7
  const int ln15 = lane & 15;
  const int quad = lane >> 4;

  // decode: qt in HIGH bits (reversed = heavy blocks first / LPT), (b,h,n) low bits
  // -> blocks sharing a K/V panel have equal bid%128 -> same XCD L2 set.
  const int bid = blockIdx.x;
  const int qt = 7 - (bid >> 7);
  const int h  = bid & 15;
  const int n  = (bid >> 4) & 3;
  const int b  = (bid >> 6) & 1;

  const int s0 = startp[0];
  const float scale = 0.08838834764831845f; // 1/sqrt(128)
  const int l0 = n * CHK + qt * BQ;
  const int rowbase = qt * BQ + wv * 16;    // within-chunk first q row of this wave

  // ---- Q fragments (16 rows/wave) from global fp32, RoPE in regs (scale folded) ----
  // A-operand layout: m = ln15 (row), k = quad*8 + j; qf[kf] covers k = kf*32+quad*8..+7
  f16x8 qf[4];
  {
    const int l = l0 + wv * 16 + ln15;
    const float* qp = q + ((size_t)(b * SEQL + l) * NH + h) * HD;
#pragma unroll
    for (int kf2 = 0; kf2 < 2; ++kf2) {
      const int c0 = kf2 * 32 + quad * 8;
      float xa[8], xb[8];
      *(f32x4*)&xa[0] = *(const f32x4*)(qp + c0);
      *(f32x4*)&xa[4] = *(const f32x4*)(qp + c0 + 4);
      *(f32x4*)&xb[0] = *(const f32x4*)(qp + c0 + 64);
      *(f32x4*)&xb[4] = *(const f32x4*)(qp + c0 + 68);
      f16x8 lo, hi;
#pragma unroll
      for (int j = 0; j < 8; ++j) {
        const int dd = c0 + j;
        float x1 = xa[j];
        float x2 = xb[j];
        float freq = exp2f(-L2B64 * (float)dd);
        float t = (float)(l + s0) * freq;
        float sn, cs;
        fast_sincos(t, &sn, &cs);
        lo[j] = (_Float16)((x1 * cs - x2 * sn) * scale);
        hi[j] = (_Float16)((x2 * cs + x1 * sn) * scale);
      }
      qf[kf2]     = lo;
      qf[kf2 + 2] = hi;
    }
  }

  f32x4 oacc[8];
  float m_run[4], l_run[4];
#pragma unroll
  for (int vq = 0; vq < 8; ++vq) { f32x4 z = {0.f, 0.f, 0.f, 0.f}; oacc[vq] = z; }
#pragma unroll
  for (int rg = 0; rg < 4; ++rg) { m_run[rg] = NEGB; l_run[rg] = 0.f; }

  const size_t tb0 = (size_t)(((b * NH + h) * NC + n)) * 16; // tile-index base
  const int ksw = (ln15 & 7) << 3;                           // read-side XOR (u16 units)

  // stage tile t: 16KB K -> sK[t&1], 16KB V -> sV[t&1]; 2KB per wave each (4 gloads/wave).
  auto stage = [&](int t) {
    const char* ks = (const char*)kr + ((tb0 + t) << 14) + wv * 2048 + lane * 16;
    const char* vs = (const char*)vt + ((tb0 + t) << 14) + wv * 2048 + lane * 16;
    char* kd = ((char*)smem) + ((t & 1) << 14) + wv * 2048;
    char* vd = ((char*)smem) + 32768 + ((t & 1) << 14) + wv * 2048;
    gload16(ks, kd);
    gload16(ks + 1024, kd + 1024);
    gload16(vs, vd);
    gload16(vs + 1024, vd + 1024);
  };

  const int ntiles = 2 * qt + 2;
  stage(0);
  // vmcnt (per-wave, in-order retire): iter top issues 4 loads for tile j+1 ->
  // outstanding 8; vmcnt(4) = tile j's 4 landed, tile j+1 stays in flight across
  // the barriers. Last iter: no prefetch -> vmcnt(0).
  for (int j = 0; j < ntiles; ++j) {
    const int cur = j & 1;
    if (j + 1 < ntiles) {
      stage(j + 1);
      asm volatile("s_waitcnt vmcnt(4)" ::: "memory"); // tile j landed
    } else {
      asm volatile("s_waitcnt vmcnt(0)" ::: "memory"); // drain
    }
    __builtin_amdgcn_s_barrier(); // B1: tile j (K and V) visible to all waves

    const unsigned short* sK  = smem + cur * 8192;
    const unsigned short* sVT = smem + 16384 + cur * 8192;
    const bool act = (j * BK <= rowbase + 15); // wave-uniform

    f32x4 sacc[4];
    if (act) {
      // ---- S = Q K^T (16 rows x 64 cols per wave) ----
#pragma unroll
      for (int ct = 0; ct < 4; ++ct) { f32x4 z = {0.f, 0.f, 0.f, 0.f}; sacc[ct] = z; }
      __builtin_amdgcn_s_setprio(1);
#pragma unroll
      for (int ct = 0; ct < 4; ++ct) {
#pragma unroll
        for (int kf = 0; kf < 4; ++kf) {
          f16x8 kb = ld8(&sK[(((ct * 16 + ln15) * 128) + kf * 32 + quad * 8) ^ ksw]);
          sacc[ct] = __builtin_amdgcn_mfma_f32_16x16x32_f16(qf[kf], kb, sacc[ct], 0, 0, 0);
        }
      }
      __builtin_amdgcn_s_setprio(0);
    }

    __builtin_amdgcn_s_barrier(); // B2: all QK reads of sK[cur] done -> reuse as sP
    unsigned short* sP = smem + cur * 8192 + wv * 1024; // this wave's 2KB (u16 units)

    if (act) {
      // ---- online softmax; C/D layout: row = quad*4+rg, col = ct*16+ln15 ----
      const int colb = j * BK + ln15;
#pragma unroll
      for (int rg = 0; rg < 4; ++rg) {
        const int row = rowbase + quad * 4 + rg;
        float mx = NEGB;
#pragma unroll
        for (int ct = 0; ct < 4; ++ct) {
          float sv = sacc[ct][rg];
          sv = (colb + ct * 16 <= row) ? sv : NEGB;
          sacc[ct][rg] = sv;
          mx = fmaxf(mx, sv);
        }
        mx = dpp16_max(mx);
        float mo = m_run[rg];
        float mn = fmaxf(mo, mx);
        m_run[rg] = mn;
        float al = __expf(mo - mn); // mo=-1e30 first tile -> 0
        float rs = 0.f;
        const int pr = quad * 4 + rg;
        const int psw = (pr & 7) << 3;
#pragma unroll
        for (int ct = 0; ct < 4; ++ct) {
          float p = __expf(sacc[ct][rg] - mn); // masked: exp(-1e30-mn) = 0
          rs += p;
          sP[(pr * 64 + ct * 16 + ln15) ^ psw] = f2h(p);
        }
        rs = dpp16_sum(rs);
        l_run[rg] = l_run[rg] * al + rs;
#pragma unroll
        for (int vq = 0; vq < 8; ++vq) oacc[vq][rg] *= al;
      }

      // per-wave P region: same-wave DS ops in order; drain writes before reads
      asm volatile("s_waitcnt lgkmcnt(0)" ::: "memory");

      // ---- O += P V ----
      __builtin_amdgcn_s_setprio(1);
#pragma unroll
      for (int kf = 0; kf < 2; ++kf) {
        f16x8 pa = ld8(&sP[(ln15 * 64 + kf * 32 + quad * 8) ^ ksw]);
#pragma unroll
        for (int vq = 0; vq < 8; ++vq) {
          f16x8 vb = ld8(&sVT[(((vq * 16 + ln15) * 64) + kf * 32 + quad * 8) ^ ksw]);
          oacc[vq] = __builtin_amdgcn_mfma_f32_16x16x32_f16(pa, vb, oacc[vq], 0, 0, 0);
        }
      }
      __builtin_amdgcn_s_setprio(0);
    }

    // B3: sP (K[cur]) reads + sV[cur] reads done -> iter j+1 may restage this half.
    __builtin_amdgcn_s_barrier();
  } // K-tile loop

  // ---- epilogue: normalize, store fp32 ----
#pragma unroll
  for (int rg = 0; rg < 4; ++rg) {
    const int l = l0 + wv * 16 + quad * 4 + rg;
    const float lr = l_run[rg];
    const float inv = (lr > 0.f) ? (1.0f / lr) : 0.f;
    float* op = out + (size_t)(b * SEQL + l) * OUTW + h * HDV + ln15;
#pragma unroll
    for (int vq = 0; vq < 8; ++vq)
      op[vq * 16] = oacc[vq][rg] * inv;
  }
}

// ======================= LEGACY (fallback when workspace too small) =======================
__global__ __launch_bounds__(256) void megalodon_attn_k(
    const float* __restrict__ q,
    const float* __restrict__ k,
    const float* __restrict__ v,
    float* __restrict__ out,
    const int* __restrict__ startp) {

  __shared__ __align__(16) unsigned short smem[27136]; // 54272 B
  unsigned short* sK  = smem;            // 8704 u16
  unsigned short* sVT = smem + 8704;     // 9216 u16
  unsigned short* sP  = smem + 17920;    // 9216 u16

  const int tid  = threadIdx.x;
  const int lane = tid & 63;
  const int wv   = tid >> 6;
  const int ln15 = lane & 15;
  const int quad = lane >> 4;

  const int bid = blockIdx.x;
  const int qt  = bid & 7;
  const int h   = (bid >> 3) & 15;
  const int n   = (bid >> 7) & 3;
  const int b   = bid >> 9;

  const int s0 = startp[0];
  const float scale = 0.08838834764831845f;
  const int l0 = n * CHK + qt * BQ;

  f16x8 qf[2][4];
#pragma unroll
  for (int rt = 0; rt < 2; ++rt) {
    const int l = l0 + wv * 32 + rt * 16 + ln15;
    const float* qp = q + ((size_t)(b * SEQL + l) * NH + h) * HD;
#pragma unroll
    for (int kf2 = 0; kf2 < 2; ++kf2) {
      const int c0 = kf2 * 32 + quad * 8;
      float xa[8], xb[8];
      *(f32x4*)&xa[0] = *(const f32x4*)(qp + c0);
      *(f32x4*)&xa[4] = *(const f32x4*)(qp + c0 + 4);
      *(f32x4*)&xb[0] = *(const f32x4*)(qp + c0 + 64);
      *(f32x4*)&xb[4] = *(const f32x4*)(qp + c0 + 68);
      f16x8 lo, hi;
#pragma unroll
      for (int j = 0; j < 8; ++j) {
        const int dd = c0 + j;
        float x1 = xa[j];
        float x2 = xb[j];
        float freq = exp2f(-L2B64 * (float)dd);
        float t = (float)(l + s0) * freq;
        float sn, cs;
        fast_sincos(t, &sn, &cs);
        lo[j] = (_Float16)((x1 * cs - x2 * sn) * scale);
        hi[j] = (_Float16)((x2 * cs + x1 * sn) * scale);
      }
      qf[rt][kf2]     = lo;
      qf[rt][kf2 + 2] = hi;
    }
  }

  f32x4 oacc[2][8];
  float m_run[2][4], l_run[2][4];
#pragma unroll
  for (int rt = 0; rt < 2; ++rt) {
#pragma unroll
    for (int vt = 0; vt < 8; ++vt) { f32x4 z = {0.f, 0.f, 0.f, 0.f}; oacc[rt][vt] = z; }
#pragma unroll
    for (int rg = 0; rg < 4; ++rg) { m_run[rt][rg] = NEGB; l_run[rt][rg] = 0.f; }
  }

  const float kfreq = exp2f(-L2B64 * (float)(tid & 63));

  const int ntiles = 2 * qt + 2;
  for (int j = 0; j < ntiles; ++j) {
    __syncthreads();
    const int kl0 = n * CHK + j * BK;

    for (int idx = tid; idx < BK * 64; idx += 256) {
      int r = idx >> 6, dd = idx & 63;
      int l = kl0 + r;
      const float* kp = k + ((size_t)(b * SEQL + l) * NH + h) * HD;
      float x1 = kp[dd];
      float x2 = kp[dd + 64];
      float t = (float)(l + s0) * kfreq;
      float sn, cs;
      fast_sincos(t, &sn, &cs);
      sK[r * KSTR + dd]      = f2h(x1 * cs - x2 * sn);
      sK[r * KSTR + dd + 64] = f2h(x2 * cs + x1 * sn);
    }
    for (int idx = tid; idx < HDV * (BK / 8); idx += 256) {
      int vc = idx & 127;
      int sk = idx >> 7;
      u16x8 vv;
#pragma unroll
      for (int i = 0; i < 8; ++i)
        vv[i] = f2h(v[((size_t)(b * SEQL + kl0 + sk * 8 + i) * NH + h) * HDV + vc]);
      *(u16x8*)&sVT[vc * VSTR + sk * 8] = vv;
    }
    __syncthreads();

    if (j * BK <= qt * BQ + wv * 32 + 31) {
      f32x4 sacc[2][4];
#pragma unroll
      for (int rt = 0; rt < 2; ++rt)
#pragma unroll
        for (int ct = 0; ct < 4; ++ct) { f32x4 z = {0.f, 0.f, 0.f, 0.f}; sacc[rt][ct] = z; }
#pragma unroll
      for (int ct = 0; ct < 4; ++ct) {
#pragma unroll
        for (int kf = 0; kf < 4; ++kf) {
          f16x8 kb = ld8(&sK[(ct * 16 + ln15) * KSTR + kf * 32 + quad * 8]);
          sacc[0][ct] = __builtin_amdgcn_mfma_f32_16x16x32_f16(qf[0][kf], kb, sacc[0][ct], 0, 0, 0);
          sacc[1][ct] = __builtin_amdgcn_mfma_f32_16x16x32_f16(qf[1][kf], kb, sacc[1][ct], 0, 0, 0);
        }
      }

      const int colb = j * BK + ln15;
      float alpha[2][4];
#pragma unroll
      for (int rt = 0; rt < 2; ++rt) {
        const int rowq = qt * BQ + wv * 32 + rt * 16 + quad * 4;
#pragma unroll
        for (int rg = 0; rg < 4; ++rg) {
          const int row = rowq + rg;
          float mx = NEGB;
#pragma unroll
          for (int ct = 0; ct < 4; ++ct) {
            float sv = sacc[rt][ct][rg];
            sv = (colb + ct * 16 <= row) ? sv : NEGB;
            sacc[rt][ct][rg] = sv;
            mx = fmaxf(mx, sv);
          }
          mx = fmaxf(mx, __shfl_xor(mx, 1));
          mx = fmaxf(mx, __shfl_xor(mx, 2));
          mx = fmaxf(mx, __shfl_xor(mx, 4));
          mx = fmaxf(mx, __shfl_xor(mx, 8));
          float mo = m_run[rt][rg];
          float mn = fmaxf(mo, mx);
          m_run[rt][rg] = mn;
          float al = __expf(mo - mn);
          alpha[rt][rg] = al;
          float rs = 0.f;
#pragma unroll
          for (int ct = 0; ct < 4; ++ct) {
            float p = __expf(sacc[rt][ct][rg] - mn);
            rs += p;
            sP[wv * (32 * VSTR) + (rt * 16 + quad * 4 + rg) * VSTR + ct * 16 + ln15] = f2h(p);
          }
          rs += __shfl_xor(rs, 1);
          rs += __shfl_xor(rs, 2);
          rs += __shfl_xor(rs, 4);
          rs += __shfl_xor(rs, 8);
          l_run[rt][rg] = l_run[rt][rg] * al + rs;
        }
      }
#pragma unroll
      for (int rt = 0; rt < 2; ++rt)
#pragma unroll
        for (int vt = 0; vt < 8; ++vt)
#pragma unroll
          for (int rg = 0; rg < 4; ++rg) oacc[rt][vt][rg] *= alpha[rt][rg];

      asm volatile("s_waitcnt lgkmcnt(0)" ::: "memory");

#pragma unroll
      for (int kf = 0; kf < 2; ++kf) {
        f16x8 pa0 = ld8(&sP[wv * (32 * VSTR) + (ln15)*VSTR + kf * 32 + quad * 8]);
        f16x8 pa1 = ld8(&sP[wv * (32 * VSTR) + (16 + ln15) * VSTR + kf * 32 + quad * 8]);
#pragma unroll
        for (int vt = 0; vt < 8; ++vt) {
          f16x8 vb = ld8(&sVT[(vt * 16 + ln15) * VSTR + kf * 32 + quad * 8]);
          oacc[0][vt] = __builtin_amdgcn_mfma_f32_16x16x32_f16(pa0, vb, oacc[0][vt], 0, 0, 0);
          oacc[1][vt] = __builtin_amdgcn_mfma_f32_16x16x32_f16(pa1, vb, oacc[1][vt], 0, 0, 0);
        }
      }
    }
  }

#pragma unroll
  for (int rt = 0; rt < 2; ++rt) {
#pragma unroll
    for (int rg = 0; rg < 4; ++rg) {
      const int l = l0 + wv * 32 + rt * 16 + quad * 4 + rg;
      const float lr = l_run[rt][rg];
      const float inv = (lr > 0.f) ? (1.0f / lr) : 0.f;
      float* op = out + (size_t)(b * SEQL + l) * OUTW + h * HDV + ln15;
#pragma unroll
      for (int vt = 0; vt < 8; ++vt)
        op[vt * 16] = oacc[rt][vt][rg] * inv;
    }
  }
}

extern "C" void kernel_launch(void* const* d_in, const int* in_sizes, int n_in,
                              void* d_out, int out_size, void* d_ws, size_t ws_size,
                              hipStream_t stream) {
  const float* q = (const float*)d_in[0];
  const float* k = (const float*)d_in[1];
  const float* v = (const float*)d_in[2];
  const int* start = (const int*)d_in[3];
  (void)in_sizes; (void)n_in; (void)out_size;

  const size_t NEED = 64ull * 1024 * 1024; // kr (32 MB) + vt (32 MB)
  if (d_ws != nullptr && ws_size >= NEED) {
    unsigned short* kr = (unsigned short*)d_ws;
    unsigned short* vt = kr + 16777216; // 32 MB in u16 units
    megalodon_prep<<<6144, 256, 0, stream>>>(k, v, kr, vt, start);
    megalodon_attn2<<<NB * 4 * NH * 8, 512, 0, stream>>>(q, kr, vt, (float*)d_out, start);
  } else {
    megalodon_attn_k<<<NB * 4 * NH * 8, 256, 0, stream>>>(q, k, v, (float*)d_out, start);
  }
}

// Round 6
// 285.705 us; speedup vs baseline: 1.1941x; 1.1941x over previous
//
#include <hip/hip_runtime.h>
#include <math.h>

#define NB 2
#define SEQL 4096
#define NH 16
#define HD 128
#define HDV 128
#define CHK 1024
#define NC 4
#define BQ 256         // rows per block (8 waves x 32 rows)
#define BK 64
#define KSTR 136       // legacy: 128 + 8 pad (u16 units)
#define VSTR 72        // legacy: 64 + 8 pad (u16 units)
#define OUTW 2048      // NH*HDV
#define NEGB (-1e30f)
#define L2B64 0.20762050593045702f  // log2(10000)/64

typedef _Float16 f16x8 __attribute__((ext_vector_type(8)));
typedef float f32x4 __attribute__((ext_vector_type(4)));
typedef unsigned short u16x8 __attribute__((ext_vector_type(8)));

static __device__ __forceinline__ unsigned short f2h(float f) {
  return __builtin_bit_cast(unsigned short, (_Float16)f);
}
static __device__ __forceinline__ f16x8 ld8(const unsigned short* p) {
  return __builtin_bit_cast(f16x8, *(const u16x8*)p);
}
// Range-reduced fast sincos: v_sin/v_cos need reduced args (ISA: reduce via fract).
static __device__ __forceinline__ void fast_sincos(float t, float* sn, float* cs) {
  const float INV2PI = 0.15915494309189535f;
  const float TWOPI  = 6.283185307179586f;
  float rev = t * INV2PI;
  rev -= floorf(rev);
  float ang = rev * TWOPI;
  *sn = __sinf(ang);
  *cs = __cosf(ang);
}
// async global->LDS, 16 B per lane; LDS dest is wave-uniform base + lane*16.
static __device__ __forceinline__ void gload16(const void* g, void* l) {
  __builtin_amdgcn_global_load_lds(
      (const __attribute__((address_space(1))) unsigned int*)g,
      (__attribute__((address_space(3))) unsigned int*)l, 16, 0, 0);
}

// 16-lane butterfly reductions on the VALU pipe via DPP.
#define DPPF(x, ctrl)                                                            \
  __builtin_bit_cast(float, __builtin_amdgcn_update_dpp(                         \
      __builtin_bit_cast(int, x), __builtin_bit_cast(int, x), ctrl, 0xF, 0xF, true))
static __device__ __forceinline__ float dpp16_max(float x) {
  x = fmaxf(x, DPPF(x, 0xB1));
  x = fmaxf(x, DPPF(x, 0x4E));
  x = fmaxf(x, DPPF(x, 0x141));
  x = fmaxf(x, DPPF(x, 0x140));
  return x;
}
static __device__ __forceinline__ float dpp16_sum(float x) {
  x += DPPF(x, 0xB1);
  x += DPPF(x, 0x4E);
  x += DPPF(x, 0x141);
  x += DPPF(x, 0x140);
  return x;
}

// ======================= PREPASS (unchanged, verified r1-r5) =======================
__global__ __launch_bounds__(256) void megalodon_prep(
    const float* __restrict__ k, const float* __restrict__ v,
    unsigned short* __restrict__ kr, unsigned short* __restrict__ vt,
    const int* __restrict__ startp) {
  const int tid = threadIdx.x;
  const int blk = blockIdx.x;
  if (blk < 4096) {
    const int s0 = startp[0];
    const int gr = blk * 32 + (tid >> 3);   // (b*L+l)*H + h
    const int c0 = (tid & 7) * 8;           // dd block [0,64)
    const int h  = gr & 15;
    const int bl = gr >> 4;
    const int l  = bl & (SEQL - 1);
    const int b  = bl >> 12;
    const int n  = l >> 10;
    const int rc = l & (CHK - 1);
    const int jt = rc >> 6;
    const int r  = rc & 63;
    const float* kp = k + (size_t)gr * HD;
    float xa[8], xb[8];
    *(f32x4*)&xa[0] = *(const f32x4*)(kp + c0);
    *(f32x4*)&xa[4] = *(const f32x4*)(kp + c0 + 4);
    *(f32x4*)&xb[0] = *(const f32x4*)(kp + c0 + 64);
    *(f32x4*)&xb[4] = *(const f32x4*)(kp + c0 + 68);
    u16x8 lo, hi;
#pragma unroll
    for (int jj = 0; jj < 8; ++jj) {
      const int dd = c0 + jj;
      float freq = exp2f(-L2B64 * (float)dd);
      float t = (float)(l + s0) * freq;
      float sn, cs;
      fast_sincos(t, &sn, &cs);
      lo[jj] = f2h(xa[jj] * cs - xb[jj] * sn);
      hi[jj] = f2h(xb[jj] * cs + xa[jj] * sn);
    }
    unsigned short* dst = kr + ((size_t)(((b * NH + h) * NC + n) * 16 + jt)) * 8192;
    const int sw = (r & 7) << 3;
    *(u16x8*)&dst[(r * 128 + c0) ^ sw]      = lo;
    *(u16x8*)&dst[(r * 128 + c0 + 64) ^ sw] = hi;
  } else {
    const int tv = blk - 4096;
    const int jt = tv & 15;
    const int n  = (tv >> 4) & 3;
    const int h  = (tv >> 6) & 15;
    const int b  = tv >> 10;
    unsigned short* dst = vt + ((size_t)(((b * NH + h) * NC + n) * 16 + jt)) * 8192;
#pragma unroll
    for (int it = 0; it < 4; ++it) {
      const int idx = tid + it * 256;
      const int vc = idx & 127;
      const int kg = idx >> 7;
      const int lbase = n * CHK + jt * 64 + kg * 8;
      u16x8 vv;
#pragma unroll
      for (int i = 0; i < 8; ++i)
        vv[i] = f2h(v[((size_t)(b * SEQL + lbase + i) * NH + h) * HDV + vc]);
      *(u16x8*)&dst[(vc * 64 + kg * 8) ^ ((vc & 7) << 3)] = vv;
    }
  }
}

// ======= MAIN v6: 8-wave 512-thr blocks, 32 Q-rows/wave (traffic-efficient r3 shape), ========
// ======= BQ=256, full K+V dbuf + DEDICATED sP (96KB LDS) -> ONE barrier per tile,     ========
// ======= stage AFTER barrier (no straggler race), no VGPR clamp (r2/r5 spill lessons). ========
__global__ __launch_bounds__(512) void megalodon_attn2(
    const float* __restrict__ q,
    const unsigned short* __restrict__ kr,
    const unsigned short* __restrict__ vt,
    float* __restrict__ out,
    const int* __restrict__ startp) {

  // LDS (u16 units): sK0 @0, sK1 @8192, sV0 @16384, sV1 @24576, sP @32768 (8w x 2048) -> 96 KiB
  __shared__ __align__(16) unsigned short smem[49152];

  const int tid  = threadIdx.x;
  const int lane = tid & 63;
  const int wv   = tid >> 6;   // 0..7
  const int ln15 = lane & 15;
  const int quad = lane >> 4;

  // decode: qt (0..3) in HIGH bits reversed (heavy blocks dispatch first / LPT).
  const int bid = blockIdx.x;
  const int qt = 3 - ((bid >> 7) & 3);
  const int h  = bid & 15;
  const int n  = (bid >> 4) & 3;
  const int b  = (bid >> 6) & 1;

  const int s0 = startp[0];
  const float scale = 0.08838834764831845f; // 1/sqrt(128)
  const int l0 = n * CHK + qt * BQ;
  const int rowbase = qt * BQ + wv * 32;    // within-chunk first q row of this wave

  // ---- Q fragments (32 rows/wave = 2 row-tiles) from global fp32, RoPE in regs ----
  f16x8 qf[2][4];
#pragma unroll
  for (int rt = 0; rt < 2; ++rt) {
    const int l = l0 + wv * 32 + rt * 16 + ln15;
    const float* qp = q + ((size_t)(b * SEQL + l) * NH + h) * HD;
#pragma unroll
    for (int kf2 = 0; kf2 < 2; ++kf2) {
      const int c0 = kf2 * 32 + quad * 8;
      float xa[8], xb[8];
      *(f32x4*)&xa[0] = *(const f32x4*)(qp + c0);
      *(f32x4*)&xa[4] = *(const f32x4*)(qp + c0 + 4);
      *(f32x4*)&xb[0] = *(const f32x4*)(qp + c0 + 64);
      *(f32x4*)&xb[4] = *(const f32x4*)(qp + c0 + 68);
      f16x8 lo, hi;
#pragma unroll
      for (int j = 0; j < 8; ++j) {
        const int dd = c0 + j;
        float x1 = xa[j];
        float x2 = xb[j];
        float freq = exp2f(-L2B64 * (float)dd);
        float t = (float)(l + s0) * freq;
        float sn, cs;
        fast_sincos(t, &sn, &cs);
        lo[j] = (_Float16)((x1 * cs - x2 * sn) * scale);
        hi[j] = (_Float16)((x2 * cs + x1 * sn) * scale);
      }
      qf[rt][kf2]     = lo;
      qf[rt][kf2 + 2] = hi;
    }
  }

  f32x4 oacc[2][8];
  float m_run[2][4], l_run[2][4];
#pragma unroll
  for (int rt = 0; rt < 2; ++rt) {
#pragma unroll
    for (int vq = 0; vq < 8; ++vq) { f32x4 z = {0.f, 0.f, 0.f, 0.f}; oacc[rt][vq] = z; }
#pragma unroll
    for (int rg = 0; rg < 4; ++rg) { m_run[rt][rg] = NEGB; l_run[rt][rg] = 0.f; }
  }

  const size_t tb0 = (size_t)(((b * NH + h) * NC + n)) * 16; // tile-index base
  const int ksw = (ln15 & 7) << 3;                           // read-side XOR (u16 units)

  // stage tile t: 16KB K -> sK[t&1], 16KB V -> sV[t&1]; 2KB each per wave (4 gloads/wave).
  auto stage = [&](int t) {
    const char* ks = (const char*)kr + ((tb0 + t) << 14) + wv * 2048 + lane * 16;
    const char* vs = (const char*)vt + ((tb0 + t) << 14) + wv * 2048 + lane * 16;
    char* kd = ((char*)smem) + ((t & 1) << 14) + wv * 2048;
    char* vd = ((char*)smem) + 32768 + ((t & 1) << 14) + wv * 2048;
    gload16(ks, kd);
    gload16(ks + 1024, kd + 1024);
    gload16(vs, vd);
    gload16(vs + 1024, vd + 1024);
  };

  const int ntiles = 4 * qt + 4;
  stage(0); // first use of buffers; no prior readers
  // Single-barrier loop. Invariants at top of iter j:
  //   - tile j's 4 loads (this wave) are the ONLY outstanding vmem -> vmcnt(0) = landed.
  //   - barrier then makes them visible AND guarantees every wave finished iter j-1
  //     reads, so stage(j+1) (issued after the barrier) can't clobber straggler reads.
  for (int j = 0; j < ntiles; ++j) {
    const int cur = j & 1;
    asm volatile("s_waitcnt vmcnt(0)" ::: "memory");
    __builtin_amdgcn_s_barrier();
    if (j + 1 < ntiles) stage(j + 1); // writes (j+1)&1 halves; in flight across body

    const unsigned short* sK  = smem + cur * 8192;
    const unsigned short* sVT = smem + 16384 + cur * 8192;
    unsigned short* sP = smem + 32768 + wv * 2048; // dedicated per-wave region
    const bool act = (j * BK <= rowbase + 31);     // wave-uniform

    if (act) {
      // ---- S = Q K^T (32 rows x 64 cols; kb shared across both row-tiles) ----
      f32x4 sacc[2][4];
#pragma unroll
      for (int rt = 0; rt < 2; ++rt)
#pragma unroll
        for (int ct = 0; ct < 4; ++ct) { f32x4 z = {0.f, 0.f, 0.f, 0.f}; sacc[rt][ct] = z; }
      __builtin_amdgcn_s_setprio(1);
#pragma unroll
      for (int ct = 0; ct < 4; ++ct) {
#pragma unroll
        for (int kf = 0; kf < 4; ++kf) {
          f16x8 kb = ld8(&sK[(((ct * 16 + ln15) * 128) + kf * 32 + quad * 8) ^ ksw]);
          sacc[0][ct] = __builtin_amdgcn_mfma_f32_16x16x32_f16(qf[0][kf], kb, sacc[0][ct], 0, 0, 0);
          sacc[1][ct] = __builtin_amdgcn_mfma_f32_16x16x32_f16(qf[1][kf], kb, sacc[1][ct], 0, 0, 0);
        }
      }
      __builtin_amdgcn_s_setprio(0);

      // ---- online softmax; C/D layout: row = quad*4+rg, col = ct*16+ln15 ----
      const int colb = j * BK + ln15;
      float alpha[2][4];
#pragma unroll
      for (int rt = 0; rt < 2; ++rt) {
        const int rowq = rowbase + rt * 16 + quad * 4;
#pragma unroll
        for (int rg = 0; rg < 4; ++rg) {
          const int row = rowq + rg;
          float mx = NEGB;
#pragma unroll
          for (int ct = 0; ct < 4; ++ct) {
            float sv = sacc[rt][ct][rg];
            sv = (colb + ct * 16 <= row) ? sv : NEGB;
            sacc[rt][ct][rg] = sv;
            mx = fmaxf(mx, sv);
          }
          mx = dpp16_max(mx);
          float mo = m_run[rt][rg];
          float mn = fmaxf(mo, mx);
          m_run[rt][rg] = mn;
          float al = __expf(mo - mn); // mo=-1e30 first tile -> 0
          alpha[rt][rg] = al;
          float rs = 0.f;
          const int prow = rt * 16 + quad * 4 + rg;
          const int psw = ((quad * 4 + rg) & 7) << 3;
#pragma unroll
          for (int ct = 0; ct < 4; ++ct) {
            float p = __expf(sacc[rt][ct][rg] - mn); // masked: exp(-1e30-mn) = 0
            rs += p;
            sP[(prow * 64 + ct * 16 + ln15) ^ psw] = f2h(p);
          }
          rs = dpp16_sum(rs);
          l_run[rt][rg] = l_run[rt][rg] * al + rs;
        }
      }
#pragma unroll
      for (int rt = 0; rt < 2; ++rt)
#pragma unroll
        for (int vq = 0; vq < 8; ++vq)
#pragma unroll
          for (int rg = 0; rg < 4; ++rg) oacc[rt][vq][rg] *= alpha[rt][rg];

      // per-wave dedicated P region: drain this wave's ds_writes before reading back
      asm volatile("s_waitcnt lgkmcnt(0)" ::: "memory");

      // ---- O += P V (vb shared across both row-tiles) ----
      __builtin_amdgcn_s_setprio(1);
#pragma unroll
      for (int kf = 0; kf < 2; ++kf) {
        f16x8 pa0 = ld8(&sP[(ln15 * 64 + kf * 32 + quad * 8) ^ ksw]);
        f16x8 pa1 = ld8(&sP[((16 + ln15) * 64 + kf * 32 + quad * 8) ^ ksw]);
#pragma unroll
        for (int vq = 0; vq < 8; ++vq) {
          f16x8 vb = ld8(&sVT[(((vq * 16 + ln15) * 64) + kf * 32 + quad * 8) ^ ksw]);
          oacc[0][vq] = __builtin_amdgcn_mfma_f32_16x16x32_f16(pa0, vb, oacc[0][vq], 0, 0, 0);
          oacc[1][vq] = __builtin_amdgcn_mfma_f32_16x16x32_f16(pa1, vb, oacc[1][vq], 0, 0, 0);
        }
      }
      __builtin_amdgcn_s_setprio(0);
    } // wave skip
  }   // K-tile loop

  // ---- epilogue: normalize, store fp32 ----
#pragma unroll
  for (int rt = 0; rt < 2; ++rt) {
#pragma unroll
    for (int rg = 0; rg < 4; ++rg) {
      const int l = l0 + wv * 32 + rt * 16 + quad * 4 + rg;
      const float lr = l_run[rt][rg];
      const float inv = (lr > 0.f) ? (1.0f / lr) : 0.f;
      float* op = out + (size_t)(b * SEQL + l) * OUTW + h * HDV + ln15;
#pragma unroll
      for (int vq = 0; vq < 8; ++vq)
        op[vq * 16] = oacc[rt][vq][rg] * inv;
    }
  }
}

// ======================= LEGACY (fallback when workspace too small) =======================
__global__ __launch_bounds__(256) void megalodon_attn_k(
    const float* __restrict__ q,
    const float* __restrict__ k,
    const float* __restrict__ v,
    float* __restrict__ out,
    const int* __restrict__ startp) {

  __shared__ __align__(16) unsigned short smem[27136]; // 54272 B
  unsigned short* sK  = smem;            // 8704 u16
  unsigned short* sVT = smem + 8704;     // 9216 u16
  unsigned short* sP  = smem + 17920;    // 9216 u16

  const int tid  = threadIdx.x;
  const int lane = tid & 63;
  const int wv   = tid >> 6;
  const int ln15 = lane & 15;
  const int quad = lane >> 4;

  const int bid = blockIdx.x;
  const int qt  = bid & 7;
  const int h   = (bid >> 3) & 15;
  const int n   = (bid >> 7) & 3;
  const int b   = bid >> 9;

  const int s0 = startp[0];
  const float scale = 0.08838834764831845f;
  const int l0 = n * CHK + qt * 128;

  f16x8 qf[2][4];
#pragma unroll
  for (int rt = 0; rt < 2; ++rt) {
    const int l = l0 + wv * 32 + rt * 16 + ln15;
    const float* qp = q + ((size_t)(b * SEQL + l) * NH + h) * HD;
#pragma unroll
    for (int kf2 = 0; kf2 < 2; ++kf2) {
      const int c0 = kf2 * 32 + quad * 8;
      float xa[8], xb[8];
      *(f32x4*)&xa[0] = *(const f32x4*)(qp + c0);
      *(f32x4*)&xa[4] = *(const f32x4*)(qp + c0 + 4);
      *(f32x4*)&xb[0] = *(const f32x4*)(qp + c0 + 64);
      *(f32x4*)&xb[4] = *(const f32x4*)(qp + c0 + 68);
      f16x8 lo, hi;
#pragma unroll
      for (int j = 0; j < 8; ++j) {
        const int dd = c0 + j;
        float x1 = xa[j];
        float x2 = xb[j];
        float freq = exp2f(-L2B64 * (float)dd);
        float t = (float)(l + s0) * freq;
        float sn, cs;
        fast_sincos(t, &sn, &cs);
        lo[j] = (_Float16)((x1 * cs - x2 * sn) * scale);
        hi[j] = (_Float16)((x2 * cs + x1 * sn) * scale);
      }
      qf[rt][kf2]     = lo;
      qf[rt][kf2 + 2] = hi;
    }
  }

  f32x4 oacc[2][8];
  float m_run[2][4], l_run[2][4];
#pragma unroll
  for (int rt = 0; rt < 2; ++rt) {
#pragma unroll
    for (int vt = 0; vt < 8; ++vt) { f32x4 z = {0.f, 0.f, 0.f, 0.f}; oacc[rt][vt] = z; }
#pragma unroll
    for (int rg = 0; rg < 4; ++rg) { m_run[rt][rg] = NEGB; l_run[rt][rg] = 0.f; }
  }

  const float kfreq = exp2f(-L2B64 * (float)(tid & 63));

  const int ntiles = 2 * qt + 2;
  for (int j = 0; j < ntiles; ++j) {
    __syncthreads();
    const int kl0 = n * CHK + j * BK;

    for (int idx = tid; idx < BK * 64; idx += 256) {
      int r = idx >> 6, dd = idx & 63;
      int l = kl0 + r;
      const float* kp = k + ((size_t)(b * SEQL + l) * NH + h) * HD;
      float x1 = kp[dd];
      float x2 = kp[dd + 64];
      float t = (float)(l + s0) * kfreq;
      float sn, cs;
      fast_sincos(t, &sn, &cs);
      sK[r * KSTR + dd]      = f2h(x1 * cs - x2 * sn);
      sK[r * KSTR + dd + 64] = f2h(x2 * cs + x1 * sn);
    }
    for (int idx = tid; idx < HDV * (BK / 8); idx += 256) {
      int vc = idx & 127;
      int sk = idx >> 7;
      u16x8 vv;
#pragma unroll
      for (int i = 0; i < 8; ++i)
        vv[i] = f2h(v[((size_t)(b * SEQL + kl0 + sk * 8 + i) * NH + h) * HDV + vc]);
      *(u16x8*)&sVT[vc * VSTR + sk * 8] = vv;
    }
    __syncthreads();

    if (j * BK <= qt * 128 + wv * 32 + 31) {
      f32x4 sacc[2][4];
#pragma unroll
      for (int rt = 0; rt < 2; ++rt)
#pragma unroll
        for (int ct = 0; ct < 4; ++ct) { f32x4 z = {0.f, 0.f, 0.f, 0.f}; sacc[rt][ct] = z; }
#pragma unroll
      for (int ct = 0; ct < 4; ++ct) {
#pragma unroll
        for (int kf = 0; kf < 4; ++kf) {
          f16x8 kb = ld8(&sK[(ct * 16 + ln15) * KSTR + kf * 32 + quad * 8]);
          sacc[0][ct] = __builtin_amdgcn_mfma_f32_16x16x32_f16(qf[0][kf], kb, sacc[0][ct], 0, 0, 0);
          sacc[1][ct] = __builtin_amdgcn_mfma_f32_16x16x32_f16(qf[1][kf], kb, sacc[1][ct], 0, 0, 0);
        }
      }

      const int colb = j * BK + ln15;
      float alpha[2][4];
#pragma unroll
      for (int rt = 0; rt < 2; ++rt) {
        const int rowq = qt * 128 + wv * 32 + rt * 16 + quad * 4;
#pragma unroll
        for (int rg = 0; rg < 4; ++rg) {
          const int row = rowq + rg;
          float mx = NEGB;
#pragma unroll
          for (int ct = 0; ct < 4; ++ct) {
            float sv = sacc[rt][ct][rg];
            sv = (colb + ct * 16 <= row) ? sv : NEGB;
            sacc[rt][ct][rg] = sv;
            mx = fmaxf(mx, sv);
          }
          mx = fmaxf(mx, __shfl_xor(mx, 1));
          mx = fmaxf(mx, __shfl_xor(mx, 2));
          mx = fmaxf(mx, __shfl_xor(mx, 4));
          mx = fmaxf(mx, __shfl_xor(mx, 8));
          float mo = m_run[rt][rg];
          float mn = fmaxf(mo, mx);
          m_run[rt][rg] = mn;
          float al = __expf(mo - mn);
          alpha[rt][rg] = al;
          float rs = 0.f;
#pragma unroll
          for (int ct = 0; ct < 4; ++ct) {
            float p = __expf(sacc[rt][ct][rg] - mn);
            rs += p;
            sP[wv * (32 * VSTR) + (rt * 16 + quad * 4 + rg) * VSTR + ct * 16 + ln15] = f2h(p);
          }
          rs += __shfl_xor(rs, 1);
          rs += __shfl_xor(rs, 2);
          rs += __shfl_xor(rs, 4);
          rs += __shfl_xor(rs, 8);
          l_run[rt][rg] = l_run[rt][rg] * al + rs;
        }
      }
#pragma unroll
      for (int rt = 0; rt < 2; ++rt)
#pragma unroll
        for (int vt = 0; vt < 8; ++vt)
#pragma unroll
          for (int rg = 0; rg < 4; ++rg) oacc[rt][vt][rg] *= alpha[rt][rg];

      asm volatile("s_waitcnt lgkmcnt(0)" ::: "memory");

#pragma unroll
      for (int kf = 0; kf < 2; ++kf) {
        f16x8 pa0 = ld8(&sP[wv * (32 * VSTR) + (ln15)*VSTR + kf * 32 + quad * 8]);
        f16x8 pa1 = ld8(&sP[wv * (32 * VSTR) + (16 + ln15) * VSTR + kf * 32 + quad * 8]);
#pragma unroll
        for (int vt = 0; vt < 8; ++vt) {
          f16x8 vb = ld8(&sVT[(vt * 16 + ln15) * VSTR + kf * 32 + quad * 8]);
          oacc[0][vt] = __builtin_amdgcn_mfma_f32_16x16x32_f16(pa0, vb, oacc[0][vt], 0, 0, 0);
          oacc[1][vt] = __builtin_amdgcn_mfma_f32_16x16x32_f16(pa1, vb, oacc[1][vt], 0, 0, 0);
        }
      }
    }
  }

#pragma unroll
  for (int rt = 0; rt < 2; ++rt) {
#pragma unroll
    for (int rg = 0; rg < 4; ++rg) {
      const int l = l0 + wv * 32 + rt * 16 + quad * 4 + rg;
      const float lr = l_run[rt][rg];
      const float inv = (lr > 0.f) ? (1.0f / lr) : 0.f;
      float* op = out + (size_t)(b * SEQL + l) * OUTW + h * HDV + ln15;
#pragma unroll
      for (int vt = 0; vt < 8; ++vt)
        op[vt * 16] = oacc[rt][vt][rg] * inv;
    }
  }
}

extern "C" void kernel_launch(void* const* d_in, const int* in_sizes, int n_in,
                              void* d_out, int out_size, void* d_ws, size_t ws_size,
                              hipStream_t stream) {
  const float* q = (const float*)d_in[0];
  const float* k = (const float*)d_in[1];
  const float* v = (const float*)d_in[2];
  const int* start = (const int*)d_in[3];
  (void)in_sizes; (void)n_in; (void)out_size;

  const size_t NEED = 64ull * 1024 * 1024; // kr (32 MB) + vt (32 MB)
  if (d_ws != nullptr && ws_size >= NEED) {
    unsigned short* kr = (unsigned short*)d_ws;
    unsigned short* vt = kr + 16777216; // 32 MB in u16 units
    megalodon_prep<<<6144, 256, 0, stream>>>(k, v, kr, vt, start);
    // 512 blocks: b(2) x n(4) x h(16) x qt(4), qt reversed in high bits (LPT)
    megalodon_attn2<<<512, 512, 0, stream>>>(q, kr, vt, (float*)d_out, start);
  } else {
    megalodon_attn_k<<<NB * 4 * NH * 8, 256, 0, stream>>>(q, k, v, (float*)d_out, start);
  }
}